// Round 9
// baseline (189.595 us; speedup 1.0000x reference)
//
#include <hip/hip_runtime.h>

#define N_NODES 10000
#define N_EDGES 640000
#define ELL_W   128    // max in-degree capacity; Poisson(64) => P(deg>127) ~ 1e-14
#define NB      157    // buckets of 64 nodes: bucket = dst >> 6
#define BCAP    4600   // per-bucket capacity (mean 4076, +8 sigma)
#define LCAP    64     // per-wg per-bucket LDS bin capacity (mean ~8 at CHUNK=1250)
#define CHUNK   1250   // edges per workgroup in phase 1 (512 wgs * 1250 = 640000)

typedef short short8 __attribute__((ext_vector_type(8)));
typedef float f32x4 __attribute__((ext_vector_type(4)));

__device__ inline float bf2f(unsigned short u) {
    return __uint_as_float(((unsigned)u) << 16);
}
// round-to-nearest-even f32 -> bf16 (data here is never NaN)
__device__ inline unsigned short f2bf(float f) {
    unsigned u = __float_as_uint(f);
    u += 0x7fffu + ((u >> 16) & 1u);
    return (unsigned short)(u >> 16);
}

// ---------------------------------------------------------------------------
// Phase 1: bin edges by dst bucket (dst>>6) via LDS, coalesced flush.
// Packed word: (src << 6) | (dst & 63). Flush is wave-parallel over buckets.
// ---------------------------------------------------------------------------
__global__ __launch_bounds__(256) void bin_edges(const int* __restrict__ src,
                                                 const int* __restrict__ dst,
                                                 int* __restrict__ gCursor,
                                                 unsigned* __restrict__ gBucket) {
    __shared__ unsigned bins[NB][LCAP];   // 40.2 KB
    __shared__ int cnt[NB];
    __shared__ int base[NB];
    int t = threadIdx.x;
    for (int i = t; i < NB; i += 256) cnt[i] = 0;
    __syncthreads();

    int e0 = blockIdx.x * CHUNK;
    int e1 = min(e0 + CHUNK, N_EDGES);
    for (int e = e0 + t; e < e1; e += 256) {
        int d = dst[e];
        int b = d >> 6;
        unsigned pk = ((unsigned)src[e] << 6) | (unsigned)(d & 63);
        int p = atomicAdd(&cnt[b], 1);
        if (p < LCAP) bins[b][p] = pk;
    }
    __syncthreads();
    for (int i = t; i < NB; i += 256) {
        int c = min(cnt[i], LCAP);
        cnt[i] = c;
        base[i] = atomicAdd(&gCursor[i], c);
    }
    __syncthreads();
    int wave = t >> 6, lane = t & 63;
    for (int b = wave; b < NB; b += 4) {
        int ba = base[b];
        int n = min(cnt[b], max(0, BCAP - ba));
        for (int i = lane; i < n; i += 64)
            gBucket[(size_t)b * BCAP + ba + i] = bins[b][i];
    }
}

// ---------------------------------------------------------------------------
// Phase 2: one workgroup per bucket; build 64 ELL rows in LDS, write coalesced.
// ---------------------------------------------------------------------------
__global__ __launch_bounds__(256) void build_ell(const unsigned* __restrict__ gBucket,
                                                 const int* __restrict__ gCursor,
                                                 unsigned short* __restrict__ ell,
                                                 int* __restrict__ deg) {
    __shared__ unsigned short rows[64 * ELL_W];  // 16 KB
    __shared__ int ldeg[64];
    int b = blockIdx.x;
    int t = threadIdx.x;
    for (int i = t; i < 64; i += 256) ldeg[i] = 0;
    __syncthreads();

    int n = min(gCursor[b], BCAP);
    const unsigned* bk = gBucket + (size_t)b * BCAP;
    for (int i = t; i < n; i += 256) {
        unsigned pk = bk[i];
        int local = pk & 63;
        int s = pk >> 6;
        int p = atomicAdd(&ldeg[local], 1);
        if (p < ELL_W) rows[local * ELL_W + p] = (unsigned short)s;
    }
    __syncthreads();

    int node0 = b * 64;
    int nNodes = min(64, N_NODES - node0);
    if (nNodes <= 0) return;
    for (int i = t; i < nNodes; i += 256)
        deg[node0 + i] = min(ldeg[i], ELL_W);
    int totalVec = nNodes * (ELL_W / 8);
    short8* dstv = (short8*)(ell + (size_t)node0 * ELL_W);
    const short8* srcv = (const short8*)rows;
    for (int i = t; i < totalVec; i += 256) dstv[i] = srcv[i];
}

// ---------------------------------------------------------------------------
// Combined prep: zero bucket cursors + cvt x fp32->bf16 + cvt/transpose weights
// ---------------------------------------------------------------------------
struct WList {
    const float* src[6];
    unsigned short* dst[6];
    int K[6];
    int off[7];  // element offsets, N == 256 for all
};

__global__ __launch_bounds__(256) void prep_kernel(const float4* __restrict__ x,
                                                   ushort4* __restrict__ xb, int n4,
                                                   WList wl, int totalW,
                                                   int* __restrict__ gCursor) {
    int idx = blockIdx.x * 256 + threadIdx.x;
    if (blockIdx.x == 0 && threadIdx.x < NB) gCursor[threadIdx.x] = 0;
    if (idx < n4) {
        float4 v = x[idx];
        ushort4 o;
        o.x = f2bf(v.x); o.y = f2bf(v.y); o.z = f2bf(v.z); o.w = f2bf(v.w);
        xb[idx] = o;
        return;
    }
    int r0 = idx - n4;
    if (r0 >= totalW) return;
    int w = 0;
    while (r0 >= wl.off[w + 1]) ++w;
    int r = r0 - wl.off[w];
    int k = r >> 8;          // N = 256
    int n = r & 255;
    wl.dst[w][(size_t)n * wl.K[w] + k] = f2bf(wl.src[w][r]);
}

// ---------------------------------------------------------------------------
// Gather aggregation (bf16, fp32 accumulate), FULL row per wave.
// UPL = uints per lane: 1 -> C=128 (256 B/row), 2 -> C=256 (512 B/row, uint2).
// One wave per node; 16 neighbors unrolled -> 16 outstanding loads.
// ---------------------------------------------------------------------------
template <int UPL>
__global__ __launch_bounds__(256) void gather_ell(const void* __restrict__ xv,
                                                  const unsigned short* __restrict__ ell,
                                                  const int* __restrict__ deg,
                                                  void* __restrict__ outv) {
    int wid = (blockIdx.x * 256 + threadIdx.x) >> 6;  // node id
    int lane = threadIdx.x & 63;
    if (wid >= N_NODES) return;
    int dg = min(deg[wid], ELL_W);
    const unsigned short* row = ell + (size_t)wid * ELL_W;

    if (UPL == 1) {
        const unsigned* x = (const unsigned*)xv;
        unsigned v = x[(size_t)wid * 64 + lane];
        float a0 = bf2f((unsigned short)(v & 0xffff));
        float a1 = bf2f((unsigned short)(v >> 16));
        int j = 0;
        for (; j + 16 <= dg; j += 16) {
            short8 iA = *(const short8*)(row + j);
            short8 iB = *(const short8*)(row + j + 8);
            unsigned vv[16];
#pragma unroll
            for (int q = 0; q < 8; ++q)
                vv[q] = x[(size_t)(unsigned short)iA[q] * 64 + lane];
#pragma unroll
            for (int q = 0; q < 8; ++q)
                vv[8 + q] = x[(size_t)(unsigned short)iB[q] * 64 + lane];
#pragma unroll
            for (int q = 0; q < 16; ++q) {
                a0 += bf2f((unsigned short)(vv[q] & 0xffff));
                a1 += bf2f((unsigned short)(vv[q] >> 16));
            }
        }
        for (; j + 4 <= dg; j += 4) {
            ushort4 sA = *(const ushort4*)(row + j);
            unsigned v0 = x[(size_t)sA.x * 64 + lane];
            unsigned v1 = x[(size_t)sA.y * 64 + lane];
            unsigned v2 = x[(size_t)sA.z * 64 + lane];
            unsigned v3 = x[(size_t)sA.w * 64 + lane];
            a0 += (bf2f((unsigned short)(v0 & 0xffff)) + bf2f((unsigned short)(v1 & 0xffff))) +
                  (bf2f((unsigned short)(v2 & 0xffff)) + bf2f((unsigned short)(v3 & 0xffff)));
            a1 += (bf2f((unsigned short)(v0 >> 16)) + bf2f((unsigned short)(v1 >> 16))) +
                  (bf2f((unsigned short)(v2 >> 16)) + bf2f((unsigned short)(v3 >> 16)));
        }
        for (; j < dg; ++j) {
            unsigned vv = x[(size_t)row[j] * 64 + lane];
            a0 += bf2f((unsigned short)(vv & 0xffff));
            a1 += bf2f((unsigned short)(vv >> 16));
        }
        ((unsigned*)outv)[(size_t)wid * 64 + lane] =
            (unsigned)f2bf(a0) | ((unsigned)f2bf(a1) << 16);
    } else {
        const uint2* x = (const uint2*)xv;
        uint2 v = x[(size_t)wid * 64 + lane];
        float a0 = bf2f((unsigned short)(v.x & 0xffff));
        float a1 = bf2f((unsigned short)(v.x >> 16));
        float a2 = bf2f((unsigned short)(v.y & 0xffff));
        float a3 = bf2f((unsigned short)(v.y >> 16));
        int j = 0;
        for (; j + 16 <= dg; j += 16) {
            short8 iA = *(const short8*)(row + j);
            short8 iB = *(const short8*)(row + j + 8);
            uint2 vv[16];
#pragma unroll
            for (int q = 0; q < 8; ++q)
                vv[q] = x[(size_t)(unsigned short)iA[q] * 64 + lane];
#pragma unroll
            for (int q = 0; q < 8; ++q)
                vv[8 + q] = x[(size_t)(unsigned short)iB[q] * 64 + lane];
#pragma unroll
            for (int q = 0; q < 16; ++q) {
                a0 += bf2f((unsigned short)(vv[q].x & 0xffff));
                a1 += bf2f((unsigned short)(vv[q].x >> 16));
                a2 += bf2f((unsigned short)(vv[q].y & 0xffff));
                a3 += bf2f((unsigned short)(vv[q].y >> 16));
            }
        }
        for (; j + 4 <= dg; j += 4) {
            ushort4 sA = *(const ushort4*)(row + j);
            uint2 v0 = x[(size_t)sA.x * 64 + lane];
            uint2 v1 = x[(size_t)sA.y * 64 + lane];
            uint2 v2 = x[(size_t)sA.z * 64 + lane];
            uint2 v3 = x[(size_t)sA.w * 64 + lane];
            a0 += (bf2f((unsigned short)(v0.x & 0xffff)) + bf2f((unsigned short)(v1.x & 0xffff))) +
                  (bf2f((unsigned short)(v2.x & 0xffff)) + bf2f((unsigned short)(v3.x & 0xffff)));
            a1 += (bf2f((unsigned short)(v0.x >> 16)) + bf2f((unsigned short)(v1.x >> 16))) +
                  (bf2f((unsigned short)(v2.x >> 16)) + bf2f((unsigned short)(v3.x >> 16)));
            a2 += (bf2f((unsigned short)(v0.y & 0xffff)) + bf2f((unsigned short)(v1.y & 0xffff))) +
                  (bf2f((unsigned short)(v2.y & 0xffff)) + bf2f((unsigned short)(v3.y & 0xffff)));
            a3 += (bf2f((unsigned short)(v0.y >> 16)) + bf2f((unsigned short)(v1.y >> 16))) +
                  (bf2f((unsigned short)(v2.y >> 16)) + bf2f((unsigned short)(v3.y >> 16)));
        }
        for (; j < dg; ++j) {
            uint2 vv = x[(size_t)row[j] * 64 + lane];
            a0 += bf2f((unsigned short)(vv.x & 0xffff));
            a1 += bf2f((unsigned short)(vv.x >> 16));
            a2 += bf2f((unsigned short)(vv.y & 0xffff));
            a3 += bf2f((unsigned short)(vv.y >> 16));
        }
        uint2 o;
        o.x = (unsigned)f2bf(a0) | ((unsigned)f2bf(a1) << 16);
        o.y = (unsigned)f2bf(a2) | ((unsigned)f2bf(a3) << 16);
        ((uint2*)outv)[(size_t)wid * 64 + lane] = o;
    }
}

// ---------------------------------------------------------------------------
// Fused MLP: out = (ReLU(A @ WA + bA)) @ WB + bB  [+ReLU2] — one dispatch.
// Block = 256 thr = 4 waves; 16 output rows per block (625 blocks -> 2.4
// waves/SIMD TLP); wave w owns col quarter w*64.. in BOTH stages. Hidden
// (16x256 bf16) in LDS, pitch 264. WtA/WtB are [N=256][K] bf16 (L2-resident).
// MFMA fragment mapping (mfma_f32_16x16x32_bf16, HW-verified):
//   A: row = lane&15, k = (lane>>4)*8 + j ; B: col = lane&15, same k
//   D: col = lane&15, row = (lane>>4)*4 + reg
// ---------------------------------------------------------------------------
template <int KSTEPS, bool RELU2, bool F32OUT>
__global__ __launch_bounds__(256) void mlp_mfma(const unsigned short* __restrict__ A,
                                                const unsigned short* __restrict__ WtA,
                                                const float* __restrict__ biasA,
                                                const unsigned short* __restrict__ WtB,
                                                const float* __restrict__ biasB,
                                                void* __restrict__ Cout) {
    constexpr int K1 = KSTEPS * 32;
    constexpr int LP = 264;  // LDS pitch in bf16 elems (528 B)
    __shared__ unsigned short hid[16 * LP];  // 8.25 KB

    int r0 = blockIdx.x * 16;
    int tid = threadIdx.x;
    int lane = tid & 63;
    int nq = tid >> 6;      // wave id = column quarter
    int lrow = lane & 15;
    int lkg = lane >> 4;
    int n0 = nq * 64;

    // ---- stage 1: hidden = ReLU(A @ WA + bA)
    {
        const short8* Ap = (const short8*)(A + (size_t)(r0 + lrow) * K1 + lkg * 8);
        const short8* Bp = (const short8*)(WtA + (size_t)(n0 + lrow) * K1 + lkg * 8);
        f32x4 acc[4] = {};
#pragma unroll
        for (int ks = 0; ks < KSTEPS; ++ks) {
            short8 a = Ap[ks * 4];
            short8 b0 = Bp[ks * 4 + 0 * 2 * K1];
            short8 b1 = Bp[ks * 4 + 1 * 2 * K1];
            short8 b2 = Bp[ks * 4 + 2 * 2 * K1];
            short8 b3 = Bp[ks * 4 + 3 * 2 * K1];
            acc[0] = __builtin_amdgcn_mfma_f32_16x16x32_bf16(a, b0, acc[0], 0, 0, 0);
            acc[1] = __builtin_amdgcn_mfma_f32_16x16x32_bf16(a, b1, acc[1], 0, 0, 0);
            acc[2] = __builtin_amdgcn_mfma_f32_16x16x32_bf16(a, b2, acc[2], 0, 0, 0);
            acc[3] = __builtin_amdgcn_mfma_f32_16x16x32_bf16(a, b3, acc[3], 0, 0, 0);
        }
        int row = lkg * 4;
#pragma unroll
        for (int nt = 0; nt < 4; ++nt) {
            int c = n0 + nt * 16 + lrow;
            float bv = biasA[c];
#pragma unroll
            for (int r = 0; r < 4; ++r) {
                float v = fmaxf(acc[nt][r] + bv, 0.f);
                hid[(row + r) * LP + c] = f2bf(v);
            }
        }
    }
    __syncthreads();

    // ---- stage 2: out = hidden @ WB + bB
    {
        const short8* Bp = (const short8*)(WtB + (size_t)(n0 + lrow) * 256 + lkg * 8);
        f32x4 acc[4] = {};
#pragma unroll
        for (int ks = 0; ks < 8; ++ks) {
            short8 a = *(const short8*)&hid[lrow * LP + ks * 32 + lkg * 8];
            short8 b0 = Bp[ks * 4 + 0 * 2 * 256];
            short8 b1 = Bp[ks * 4 + 1 * 2 * 256];
            short8 b2 = Bp[ks * 4 + 2 * 2 * 256];
            short8 b3 = Bp[ks * 4 + 3 * 2 * 256];
            acc[0] = __builtin_amdgcn_mfma_f32_16x16x32_bf16(a, b0, acc[0], 0, 0, 0);
            acc[1] = __builtin_amdgcn_mfma_f32_16x16x32_bf16(a, b1, acc[1], 0, 0, 0);
            acc[2] = __builtin_amdgcn_mfma_f32_16x16x32_bf16(a, b2, acc[2], 0, 0, 0);
            acc[3] = __builtin_amdgcn_mfma_f32_16x16x32_bf16(a, b3, acc[3], 0, 0, 0);
        }
        int orow = r0 + lkg * 4;
#pragma unroll
        for (int nt = 0; nt < 4; ++nt) {
            int c = n0 + nt * 16 + lrow;
            float bv = biasB[c];
#pragma unroll
            for (int r = 0; r < 4; ++r) {
                int grow = orow + r;
                if (grow >= N_NODES) continue;
                float v = acc[nt][r] + bv;
                if (RELU2) v = fmaxf(v, 0.f);
                if (F32OUT)
                    ((float*)Cout)[(size_t)grow * 256 + c] = v;
                else
                    ((unsigned short*)Cout)[(size_t)grow * 256 + c] = f2bf(v);
            }
        }
    }
}

// ---------------------------------------------------------------------------
extern "C" void kernel_launch(void* const* d_in, const int* in_sizes, int n_in,
                              void* d_out, int out_size, void* d_ws, size_t ws_size,
                              hipStream_t stream) {
    const float* x   = (const float*)d_in[0];
    const int*   ei  = (const int*)d_in[1];
    const int*   src = ei;
    const int*   dst = ei + N_EDGES;
    const float* W0a = (const float*)d_in[2];
    const float* b0a = (const float*)d_in[3];
    const float* W0b = (const float*)d_in[4];
    const float* b0b = (const float*)d_in[5];
    const float* W1a = (const float*)d_in[6];
    const float* b1a = (const float*)d_in[7];
    const float* W1b = (const float*)d_in[8];
    const float* b1b = (const float*)d_in[9];
    const float* W2a = (const float*)d_in[10];
    const float* b2a = (const float*)d_in[11];
    const float* W2b = (const float*)d_in[12];
    const float* b2b = (const float*)d_in[13];

    char* ws = (char*)d_ws;
    size_t off = 0;
    auto alloc = [&](size_t bytes) {
        void* p = ws + off;
        off += (bytes + 255) & ~(size_t)255;
        return p;
    };
    unsigned short* xb    = (unsigned short*)alloc((size_t)N_NODES * 128 * 2);
    unsigned short* B0    = (unsigned short*)alloc((size_t)N_NODES * 256 * 2);
    unsigned short* B2    = (unsigned short*)alloc((size_t)N_NODES * 256 * 2);
    unsigned short* Wt0a  = (unsigned short*)alloc(256 * 128 * 2);
    unsigned short* Wt0b  = (unsigned short*)alloc(256 * 256 * 2);
    unsigned short* Wt1a  = (unsigned short*)alloc(256 * 256 * 2);
    unsigned short* Wt1b  = (unsigned short*)alloc(256 * 256 * 2);
    unsigned short* Wt2a  = (unsigned short*)alloc(256 * 256 * 2);
    unsigned short* Wt2b  = (unsigned short*)alloc(256 * 256 * 2);
    int*            deg   = (int*)alloc(N_NODES * 4);
    unsigned short* ell   = (unsigned short*)alloc((size_t)N_NODES * ELL_W * 2);
    int*            gCur  = (int*)alloc(NB * 4);
    unsigned*       gBkt  = (unsigned*)alloc((size_t)NB * BCAP * 4);

    int gatherBlocks = (N_NODES + 3) / 4;   // 2500 (4 waves/block, 1 node/wave)
    int mlpBlocks = (N_NODES + 15) / 16;    // 625

    // ---- prep: zero cursors + x->bf16 + weight transpose/convert (1 dispatch)
    WList wl;
    wl.src[0] = W0a; wl.dst[0] = Wt0a; wl.K[0] = 128;
    wl.src[1] = W0b; wl.dst[1] = Wt0b; wl.K[1] = 256;
    wl.src[2] = W1a; wl.dst[2] = Wt1a; wl.K[2] = 256;
    wl.src[3] = W1b; wl.dst[3] = Wt1b; wl.K[3] = 256;
    wl.src[4] = W2a; wl.dst[4] = Wt2a; wl.K[4] = 256;
    wl.src[5] = W2b; wl.dst[5] = Wt2b; wl.K[5] = 256;
    int totalW = 0;
    for (int i = 0; i < 6; ++i) { wl.off[i] = totalW; totalW += wl.K[i] * 256; }
    wl.off[6] = totalW;
    int n4 = N_NODES * 128 / 4;
    int prepTasks = n4 + totalW;
    prep_kernel<<<(prepTasks + 255) / 256, 256, 0, stream>>>(
        (const float4*)x, (ushort4*)xb, n4, wl, totalW, gCur);

    // ---- ELL build ----
    bin_edges<<<(N_EDGES + CHUNK - 1) / CHUNK, 256, 0, stream>>>(src, dst, gCur, gBkt);
    build_ell<<<NB, 256, 0, stream>>>(gBkt, gCur, ell, deg);

    // ---- Layer 0 (C_in = 128) ----
    gather_ell<1><<<gatherBlocks, 256, 0, stream>>>(xb, ell, deg, B0);
    mlp_mfma<4, true, false><<<mlpBlocks, 256, 0, stream>>>(B0, Wt0a, b0a, Wt0b, b0b, B2);
    // ---- Layer 1 (C = 256) ----
    gather_ell<2><<<gatherBlocks, 256, 0, stream>>>(B2, ell, deg, B0);
    mlp_mfma<8, true, false><<<mlpBlocks, 256, 0, stream>>>(B0, Wt1a, b1a, Wt1b, b1b, B2);
    // ---- Layer 2 (C = 256, final out fp32, no ReLU) ----
    gather_ell<2><<<gatherBlocks, 256, 0, stream>>>(B2, ell, deg, B0);
    mlp_mfma<8, false, true><<<mlpBlocks, 256, 0, stream>>>(B0, Wt2a, b2a, Wt2b, b2b, d_out);
}

// Round 10
// 160.987 us; speedup vs baseline: 1.1777x; 1.1777x over previous
//
#include <hip/hip_runtime.h>

#define N_NODES 10000
#define N_EDGES 640000
#define ELL_W   128    // max in-degree capacity; Poisson(64) => P(deg>127) ~ 1e-14
#define NB      157    // buckets of 64 nodes: bucket = dst >> 6
#define BCAP    4600   // per-bucket capacity (mean 4076, +8 sigma)
#define LCAP    80     // per-wg per-bucket LDS bin capacity (mean ~16, +16 sigma)
#define CHUNK   2500   // edges per workgroup in phase 1 (256 wgs * 2500 = 640000)

typedef short short8 __attribute__((ext_vector_type(8)));
typedef float f32x4 __attribute__((ext_vector_type(4)));

__device__ inline float bf2f(unsigned short u) {
    return __uint_as_float(((unsigned)u) << 16);
}
// round-to-nearest-even f32 -> bf16 (data here is never NaN)
__device__ inline unsigned short f2bf(float f) {
    unsigned u = __float_as_uint(f);
    u += 0x7fffu + ((u >> 16) & 1u);
    return (unsigned short)(u >> 16);
}

// ---------------------------------------------------------------------------
// Phase 1: bin edges by dst bucket (dst>>6) via LDS, coalesced flush.
// Packed word: (src << 6) | (dst & 63). Flush is wave-parallel over buckets.
// ---------------------------------------------------------------------------
__global__ __launch_bounds__(256) void bin_edges(const int* __restrict__ src,
                                                 const int* __restrict__ dst,
                                                 int* __restrict__ gCursor,
                                                 unsigned* __restrict__ gBucket) {
    __shared__ unsigned bins[NB][LCAP];
    __shared__ int cnt[NB];
    __shared__ int base[NB];
    int t = threadIdx.x;
    for (int i = t; i < NB; i += 256) cnt[i] = 0;
    __syncthreads();

    int e0 = blockIdx.x * CHUNK;
    int e1 = min(e0 + CHUNK, N_EDGES);
    for (int e = e0 + t; e < e1; e += 256) {
        int d = dst[e];
        int b = d >> 6;
        unsigned pk = ((unsigned)src[e] << 6) | (unsigned)(d & 63);
        int p = atomicAdd(&cnt[b], 1);
        if (p < LCAP) bins[b][p] = pk;
    }
    __syncthreads();
    for (int i = t; i < NB; i += 256) {
        int c = min(cnt[i], LCAP);
        cnt[i] = c;
        base[i] = atomicAdd(&gCursor[i], c);
    }
    __syncthreads();
    int wave = t >> 6, lane = t & 63;
    for (int b = wave; b < NB; b += 4) {
        int ba = base[b];
        int n = min(cnt[b], max(0, BCAP - ba));
        for (int i = lane; i < n; i += 64)
            gBucket[(size_t)b * BCAP + ba + i] = bins[b][i];
    }
}

// ---------------------------------------------------------------------------
// Phase 2: one workgroup per bucket; build 64 ELL rows in LDS, write coalesced.
// ---------------------------------------------------------------------------
__global__ __launch_bounds__(256) void build_ell(const unsigned* __restrict__ gBucket,
                                                 const int* __restrict__ gCursor,
                                                 unsigned short* __restrict__ ell,
                                                 int* __restrict__ deg) {
    __shared__ unsigned short rows[64 * ELL_W];  // 16 KB
    __shared__ int ldeg[64];
    int b = blockIdx.x;
    int t = threadIdx.x;
    for (int i = t; i < 64; i += 256) ldeg[i] = 0;
    __syncthreads();

    int n = min(gCursor[b], BCAP);
    const unsigned* bk = gBucket + (size_t)b * BCAP;
    for (int i = t; i < n; i += 256) {
        unsigned pk = bk[i];
        int local = pk & 63;
        int s = pk >> 6;
        int p = atomicAdd(&ldeg[local], 1);
        if (p < ELL_W) rows[local * ELL_W + p] = (unsigned short)s;
    }
    __syncthreads();

    int node0 = b * 64;
    int nNodes = min(64, N_NODES - node0);
    if (nNodes <= 0) return;
    for (int i = t; i < nNodes; i += 256)
        deg[node0 + i] = min(ldeg[i], ELL_W);
    int totalVec = nNodes * (ELL_W / 8);
    short8* dstv = (short8*)(ell + (size_t)node0 * ELL_W);
    const short8* srcv = (const short8*)rows;
    for (int i = t; i < totalVec; i += 256) dstv[i] = srcv[i];
}

// ---------------------------------------------------------------------------
// Combined prep: zero bucket cursors + cvt x fp32->bf16 + cvt/transpose weights
// ---------------------------------------------------------------------------
struct WList {
    const float* src[6];
    unsigned short* dst[6];
    int K[6];
    int off[7];  // element offsets, N == 256 for all
};

__global__ __launch_bounds__(256) void prep_kernel(const float4* __restrict__ x,
                                                   ushort4* __restrict__ xb, int n4,
                                                   WList wl, int totalW,
                                                   int* __restrict__ gCursor) {
    int idx = blockIdx.x * 256 + threadIdx.x;
    if (blockIdx.x == 0 && threadIdx.x < NB) gCursor[threadIdx.x] = 0;
    if (idx < n4) {
        float4 v = x[idx];
        ushort4 o;
        o.x = f2bf(v.x); o.y = f2bf(v.y); o.z = f2bf(v.z); o.w = f2bf(v.w);
        xb[idx] = o;
        return;
    }
    int r0 = idx - n4;
    if (r0 >= totalW) return;
    int w = 0;
    while (r0 >= wl.off[w + 1]) ++w;
    int r = r0 - wl.off[w];
    int k = r >> 8;          // N = 256
    int n = r & 255;
    wl.dst[w][(size_t)n * wl.K[w] + k] = f2bf(wl.src[w][r]);
}

// ---------------------------------------------------------------------------
// Gather aggregation (bf16, fp32 accumulate), 128 channels per wave-pass so the
// random-row working set (2.56 MB) stays L2-resident per XCD (r9 proved the
// full-row 5.12 MB variant regresses: latency-bound on L2 misses).
// One wave per (node, half); blockIdx.y = half. 32 outstanding loads/batch.
// ---------------------------------------------------------------------------
template <int U2STRIDE>
__global__ __launch_bounds__(256) void gather_ell(const unsigned* __restrict__ x,
                                                  const unsigned short* __restrict__ ell,
                                                  const int* __restrict__ deg,
                                                  unsigned* __restrict__ out) {
    int wid = (blockIdx.x * 256 + threadIdx.x) >> 6;  // node id
    int lane = threadIdx.x & 63;
    if (wid >= N_NODES) return;
    int off = blockIdx.y * 64 + lane;  // uint offset within row

    unsigned v = x[(size_t)wid * U2STRIDE + off];
    float a0 = bf2f((unsigned short)(v & 0xffff));
    float a1 = bf2f((unsigned short)(v >> 16));

    int dg = min(deg[wid], ELL_W);
    const unsigned short* row = ell + (size_t)wid * ELL_W;

    int j = 0;
    // 32-deep batches: 32 row-loads in flight against ~L2 latency
    for (; j + 32 <= dg; j += 32) {
        short8 i0 = *(const short8*)(row + j);
        short8 i1 = *(const short8*)(row + j + 8);
        short8 i2 = *(const short8*)(row + j + 16);
        short8 i3 = *(const short8*)(row + j + 24);
        unsigned vv[32];
#pragma unroll
        for (int q = 0; q < 8; ++q)
            vv[q] = x[(size_t)(unsigned short)i0[q] * U2STRIDE + off];
#pragma unroll
        for (int q = 0; q < 8; ++q)
            vv[8 + q] = x[(size_t)(unsigned short)i1[q] * U2STRIDE + off];
#pragma unroll
        for (int q = 0; q < 8; ++q)
            vv[16 + q] = x[(size_t)(unsigned short)i2[q] * U2STRIDE + off];
#pragma unroll
        for (int q = 0; q < 8; ++q)
            vv[24 + q] = x[(size_t)(unsigned short)i3[q] * U2STRIDE + off];
#pragma unroll
        for (int q = 0; q < 32; ++q) {
            a0 += bf2f((unsigned short)(vv[q] & 0xffff));
            a1 += bf2f((unsigned short)(vv[q] >> 16));
        }
    }
    for (; j + 16 <= dg; j += 16) {
        short8 iA = *(const short8*)(row + j);
        short8 iB = *(const short8*)(row + j + 8);
        unsigned vv[16];
#pragma unroll
        for (int q = 0; q < 8; ++q)
            vv[q] = x[(size_t)(unsigned short)iA[q] * U2STRIDE + off];
#pragma unroll
        for (int q = 0; q < 8; ++q)
            vv[8 + q] = x[(size_t)(unsigned short)iB[q] * U2STRIDE + off];
#pragma unroll
        for (int q = 0; q < 16; ++q) {
            a0 += bf2f((unsigned short)(vv[q] & 0xffff));
            a1 += bf2f((unsigned short)(vv[q] >> 16));
        }
    }
    for (; j + 4 <= dg; j += 4) {
        ushort4 sA = *(const ushort4*)(row + j);
        unsigned v0 = x[(size_t)sA.x * U2STRIDE + off];
        unsigned v1 = x[(size_t)sA.y * U2STRIDE + off];
        unsigned v2 = x[(size_t)sA.z * U2STRIDE + off];
        unsigned v3 = x[(size_t)sA.w * U2STRIDE + off];
        a0 += (bf2f((unsigned short)(v0 & 0xffff)) + bf2f((unsigned short)(v1 & 0xffff))) +
              (bf2f((unsigned short)(v2 & 0xffff)) + bf2f((unsigned short)(v3 & 0xffff)));
        a1 += (bf2f((unsigned short)(v0 >> 16)) + bf2f((unsigned short)(v1 >> 16))) +
              (bf2f((unsigned short)(v2 >> 16)) + bf2f((unsigned short)(v3 >> 16)));
    }
    for (; j < dg; ++j) {
        unsigned vv = x[(size_t)row[j] * U2STRIDE + off];
        a0 += bf2f((unsigned short)(vv & 0xffff));
        a1 += bf2f((unsigned short)(vv >> 16));
    }
    unsigned o = (unsigned)f2bf(a0) | ((unsigned)f2bf(a1) << 16);
    out[(size_t)wid * U2STRIDE + off] = o;
}

// ---------------------------------------------------------------------------
// Fused MLP: out = (ReLU(A @ WA + bA)) @ WB + bB  [+ReLU2] — one dispatch.
// Block = 256 thr = 4 waves; 32 output rows per block; wave w owns col quarter
// w*64..w*64+63 in BOTH stages. Hidden (32x256 bf16) staged in LDS, pitch 264.
// WtA/WtB are [N=256][K] bf16 (L2-resident).
// MFMA fragment mapping (mfma_f32_16x16x32_bf16, HW-verified):
//   A: row = lane&15, k = (lane>>4)*8 + j ; B: col = lane&15, same k
//   D: col = lane&15, row = (lane>>4)*4 + reg
// ---------------------------------------------------------------------------
template <int KSTEPS, bool RELU2, bool F32OUT>
__global__ __launch_bounds__(256) void mlp_mfma(const unsigned short* __restrict__ A,
                                                const unsigned short* __restrict__ WtA,
                                                const float* __restrict__ biasA,
                                                const unsigned short* __restrict__ WtB,
                                                const float* __restrict__ biasB,
                                                void* __restrict__ Cout) {
    constexpr int K1 = KSTEPS * 32;
    constexpr int LP = 264;  // LDS pitch in bf16 elems (528 B)
    __shared__ unsigned short hid[32 * LP];  // 16.5 KB

    int r0 = blockIdx.x * 32;
    int tid = threadIdx.x;
    int lane = tid & 63;
    int nq = tid >> 6;      // wave id = column quarter
    int lrow = lane & 15;
    int lkg = lane >> 4;
    int n0 = nq * 64;

    // ---- stage 1: hidden = ReLU(A @ WA + bA)
    {
        const short8* Ap0 = (const short8*)(A + (size_t)(r0 + lrow) * K1 + lkg * 8);
        const short8* Ap1 = (const short8*)(A + (size_t)(r0 + 16 + lrow) * K1 + lkg * 8);
        const short8* Bp = (const short8*)(WtA + (size_t)(n0 + lrow) * K1 + lkg * 8);
        f32x4 acc[2][4] = {};
#pragma unroll
        for (int ks = 0; ks < KSTEPS; ++ks) {
            short8 a0 = Ap0[ks * 4];
            short8 a1 = Ap1[ks * 4];
            short8 b0 = Bp[ks * 4 + 0 * 2 * K1];
            short8 b1 = Bp[ks * 4 + 1 * 2 * K1];
            short8 b2 = Bp[ks * 4 + 2 * 2 * K1];
            short8 b3 = Bp[ks * 4 + 3 * 2 * K1];
            acc[0][0] = __builtin_amdgcn_mfma_f32_16x16x32_bf16(a0, b0, acc[0][0], 0, 0, 0);
            acc[0][1] = __builtin_amdgcn_mfma_f32_16x16x32_bf16(a0, b1, acc[0][1], 0, 0, 0);
            acc[0][2] = __builtin_amdgcn_mfma_f32_16x16x32_bf16(a0, b2, acc[0][2], 0, 0, 0);
            acc[0][3] = __builtin_amdgcn_mfma_f32_16x16x32_bf16(a0, b3, acc[0][3], 0, 0, 0);
            acc[1][0] = __builtin_amdgcn_mfma_f32_16x16x32_bf16(a1, b0, acc[1][0], 0, 0, 0);
            acc[1][1] = __builtin_amdgcn_mfma_f32_16x16x32_bf16(a1, b1, acc[1][1], 0, 0, 0);
            acc[1][2] = __builtin_amdgcn_mfma_f32_16x16x32_bf16(a1, b2, acc[1][2], 0, 0, 0);
            acc[1][3] = __builtin_amdgcn_mfma_f32_16x16x32_bf16(a1, b3, acc[1][3], 0, 0, 0);
        }
#pragma unroll
        for (int rg = 0; rg < 2; ++rg) {
            int row = rg * 16 + lkg * 4;
#pragma unroll
            for (int nt = 0; nt < 4; ++nt) {
                int c = n0 + nt * 16 + lrow;
                float bv = biasA[c];
#pragma unroll
                for (int r = 0; r < 4; ++r) {
                    float v = fmaxf(acc[rg][nt][r] + bv, 0.f);
                    hid[(row + r) * LP + c] = f2bf(v);
                }
            }
        }
    }
    __syncthreads();

    // ---- stage 2: out = hidden @ WB + bB
    {
        const short8* Bp = (const short8*)(WtB + (size_t)(n0 + lrow) * 256 + lkg * 8);
        f32x4 acc[2][4] = {};
#pragma unroll
        for (int ks = 0; ks < 8; ++ks) {
            short8 a0 = *(const short8*)&hid[lrow * LP + ks * 32 + lkg * 8];
            short8 a1 = *(const short8*)&hid[(16 + lrow) * LP + ks * 32 + lkg * 8];
            short8 b0 = Bp[ks * 4 + 0 * 2 * 256];
            short8 b1 = Bp[ks * 4 + 1 * 2 * 256];
            short8 b2 = Bp[ks * 4 + 2 * 2 * 256];
            short8 b3 = Bp[ks * 4 + 3 * 2 * 256];
            acc[0][0] = __builtin_amdgcn_mfma_f32_16x16x32_bf16(a0, b0, acc[0][0], 0, 0, 0);
            acc[0][1] = __builtin_amdgcn_mfma_f32_16x16x32_bf16(a0, b1, acc[0][1], 0, 0, 0);
            acc[0][2] = __builtin_amdgcn_mfma_f32_16x16x32_bf16(a0, b2, acc[0][2], 0, 0, 0);
            acc[0][3] = __builtin_amdgcn_mfma_f32_16x16x32_bf16(a0, b3, acc[0][3], 0, 0, 0);
            acc[1][0] = __builtin_amdgcn_mfma_f32_16x16x32_bf16(a1, b0, acc[1][0], 0, 0, 0);
            acc[1][1] = __builtin_amdgcn_mfma_f32_16x16x32_bf16(a1, b1, acc[1][1], 0, 0, 0);
            acc[1][2] = __builtin_amdgcn_mfma_f32_16x16x32_bf16(a1, b2, acc[1][2], 0, 0, 0);
            acc[1][3] = __builtin_amdgcn_mfma_f32_16x16x32_bf16(a1, b3, acc[1][3], 0, 0, 0);
        }
#pragma unroll
        for (int rg = 0; rg < 2; ++rg) {
            int orow = r0 + rg * 16 + lkg * 4;
#pragma unroll
            for (int nt = 0; nt < 4; ++nt) {
                int c = n0 + nt * 16 + lrow;
                float bv = biasB[c];
#pragma unroll
                for (int r = 0; r < 4; ++r) {
                    int grow = orow + r;
                    if (grow >= N_NODES) continue;
                    float v = acc[rg][nt][r] + bv;
                    if (RELU2) v = fmaxf(v, 0.f);
                    if (F32OUT)
                        ((float*)Cout)[(size_t)grow * 256 + c] = v;
                    else
                        ((unsigned short*)Cout)[(size_t)grow * 256 + c] = f2bf(v);
                }
            }
        }
    }
}

// ---------------------------------------------------------------------------
extern "C" void kernel_launch(void* const* d_in, const int* in_sizes, int n_in,
                              void* d_out, int out_size, void* d_ws, size_t ws_size,
                              hipStream_t stream) {
    const float* x   = (const float*)d_in[0];
    const int*   ei  = (const int*)d_in[1];
    const int*   src = ei;
    const int*   dst = ei + N_EDGES;
    const float* W0a = (const float*)d_in[2];
    const float* b0a = (const float*)d_in[3];
    const float* W0b = (const float*)d_in[4];
    const float* b0b = (const float*)d_in[5];
    const float* W1a = (const float*)d_in[6];
    const float* b1a = (const float*)d_in[7];
    const float* W1b = (const float*)d_in[8];
    const float* b1b = (const float*)d_in[9];
    const float* W2a = (const float*)d_in[10];
    const float* b2a = (const float*)d_in[11];
    const float* W2b = (const float*)d_in[12];
    const float* b2b = (const float*)d_in[13];

    char* ws = (char*)d_ws;
    size_t off = 0;
    auto alloc = [&](size_t bytes) {
        void* p = ws + off;
        off += (bytes + 255) & ~(size_t)255;
        return p;
    };
    unsigned short* xb    = (unsigned short*)alloc((size_t)N_NODES * 128 * 2);
    unsigned short* B0    = (unsigned short*)alloc((size_t)N_NODES * 256 * 2);
    unsigned short* B2    = (unsigned short*)alloc((size_t)N_NODES * 256 * 2);
    unsigned short* Wt0a  = (unsigned short*)alloc(256 * 128 * 2);
    unsigned short* Wt0b  = (unsigned short*)alloc(256 * 256 * 2);
    unsigned short* Wt1a  = (unsigned short*)alloc(256 * 256 * 2);
    unsigned short* Wt1b  = (unsigned short*)alloc(256 * 256 * 2);
    unsigned short* Wt2a  = (unsigned short*)alloc(256 * 256 * 2);
    unsigned short* Wt2b  = (unsigned short*)alloc(256 * 256 * 2);
    int*            deg   = (int*)alloc(N_NODES * 4);
    unsigned short* ell   = (unsigned short*)alloc((size_t)N_NODES * ELL_W * 2);
    int*            gCur  = (int*)alloc(NB * 4);
    unsigned*       gBkt  = (unsigned*)alloc((size_t)NB * BCAP * 4);

    dim3 gatherGrid1((N_NODES + 3) / 4, 1);        // C=128: one half
    dim3 gatherGrid2((N_NODES + 3) / 4, 2);        // C=256: two halves
    int mlpBlocks = (N_NODES + 31) / 32;           // 313

    // ---- prep: zero cursors + x->bf16 + weight transpose/convert (1 dispatch)
    WList wl;
    wl.src[0] = W0a; wl.dst[0] = Wt0a; wl.K[0] = 128;
    wl.src[1] = W0b; wl.dst[1] = Wt0b; wl.K[1] = 256;
    wl.src[2] = W1a; wl.dst[2] = Wt1a; wl.K[2] = 256;
    wl.src[3] = W1b; wl.dst[3] = Wt1b; wl.K[3] = 256;
    wl.src[4] = W2a; wl.dst[4] = Wt2a; wl.K[4] = 256;
    wl.src[5] = W2b; wl.dst[5] = Wt2b; wl.K[5] = 256;
    int totalW = 0;
    for (int i = 0; i < 6; ++i) { wl.off[i] = totalW; totalW += wl.K[i] * 256; }
    wl.off[6] = totalW;
    int n4 = N_NODES * 128 / 4;
    int prepTasks = n4 + totalW;
    prep_kernel<<<(prepTasks + 255) / 256, 256, 0, stream>>>(
        (const float4*)x, (ushort4*)xb, n4, wl, totalW, gCur);

    // ---- ELL build ----
    bin_edges<<<(N_EDGES + CHUNK - 1) / CHUNK, 256, 0, stream>>>(src, dst, gCur, gBkt);
    build_ell<<<NB, 256, 0, stream>>>(gBkt, gCur, ell, deg);

    // ---- Layer 0 (C_in = 128) ----
    gather_ell<64><<<gatherGrid1, 256, 0, stream>>>((const unsigned*)xb, ell, deg, (unsigned*)B0);
    mlp_mfma<4, true, false><<<mlpBlocks, 256, 0, stream>>>(B0, Wt0a, b0a, Wt0b, b0b, B2);
    // ---- Layer 1 (C = 256) ----
    gather_ell<128><<<gatherGrid2, 256, 0, stream>>>((const unsigned*)B2, ell, deg, (unsigned*)B0);
    mlp_mfma<8, true, false><<<mlpBlocks, 256, 0, stream>>>(B0, Wt1a, b1a, Wt1b, b1b, B2);
    // ---- Layer 2 (C = 256, final out fp32, no ReLU) ----
    gather_ell<128><<<gatherGrid2, 256, 0, stream>>>((const unsigned*)B2, ell, deg, (unsigned*)B0);
    mlp_mfma<8, false, true><<<mlpBlocks, 256, 0, stream>>>(B0, Wt2a, b2a, Wt2b, b2b, d_out);
}